// Round 5
// baseline (839.658 us; speedup 1.0000x reference)
//
#include <hip/hip_runtime.h>
#include <math.h>

#define NSV 512

// ---------------------------------------------------------------------------
// Device-scope grid barrier (persistent-kernel style). Module globals are
// zero-initialized at load; the exit protocol resets them at the end of every
// launch, so each graph replay starts from a clean state. Release/acquire
// __threadfence() around the counter handles cross-XCD L2 non-coherence.
// ---------------------------------------------------------------------------
__device__ unsigned g_bar  = 0;
__device__ unsigned g_exit = 0;

__device__ __forceinline__ void gsync(unsigned target) {
    __threadfence();                       // release this block's writes
    __syncthreads();
    if (threadIdx.x == 0) {
        atomicAdd(&g_bar, 1u);
        while (__hip_atomic_load(&g_bar, __ATOMIC_ACQUIRE,
                                 __HIP_MEMORY_SCOPE_AGENT) < target)
            __builtin_amdgcn_s_sleep(2);
    }
    __syncthreads();
    __threadfence();                       // acquire: see other blocks' writes
}

// ---------------------------------------------------------------------------
// Role: s-stream GEMM (A). Tile 8e x 64o, 128 blocks (et=b>>3, ot=b&7).
// out[e][o] = tanh(t1[o] + [pme(2FP)|sv(FS)] . Vw[2FS:,o])
// t1[o] = Vb[o] + smean_flat . Vw[0:2FS,o], smean from sm0 (L0) or psum rows.
// Also writes per-block column sums to psumOut for the NEXT layer's t1.
// ---------------------------------------------------------------------------
template<int FS, int FP, bool L0>
__device__ void a_role(int b, const float* __restrict__ svIn,
                       const float* __restrict__ pmeIn,
                       const float* __restrict__ smSrc,
                       const float* __restrict__ Vw, const float* __restrict__ Vb,
                       float* __restrict__ svOut, float* __restrict__ psumOut,
                       float* sh)
{
    constexpr int KP = 2*FP + FS;          // 136 (L0) or 640
    const int t  = threadIdx.x;
    const int et = b >> 3, ot = b & 7;
    const int e0 = et * 8;
    const int o0 = ot * 64;
    const int ol = t & 63;
    const int o  = o0 + ol;
    const int wv = t >> 6;                 // 0..7
    float* As  = sh;                       // 8*KP
    float* smL = As + 8*KP;                // 2*FS
    float* red = smL + 2*FS;               // 512
    float* t1L = red + 512;                // 64

    for (int idx = t; idx < 8*2*FP; idx += 512)
        As[(idx/(2*FP))*KP + idx%(2*FP)] =
            pmeIn[(size_t)(e0 + idx/(2*FP))*(2*FP) + idx%(2*FP)];
    for (int idx = t; idx < 8*FS; idx += 512)
        As[(idx/FS)*KP + 2*FP + idx%FS] = svIn[(size_t)(e0 + idx/FS)*FS + idx%FS];
    if (L0) {
        for (int idx = t; idx < 2*FS; idx += 512) smL[idx] = smSrc[idx];
    } else {
        for (int idx = t; idx < 2*FS; idx += 512) {
            int col = (idx < FS) ? idx : idx - FS;
            int r0  = (idx < FS) ? 0 : 8;
            float s = 0.f;
            #pragma unroll
            for (int k2 = 0; k2 < 8; ++k2) s += smSrc[(r0+k2)*NSV + col];
            smL[idx] = s * 0.015625f;
        }
    }
    __syncthreads();

    {   // t1 partials: K = 2*FS over the 8 waves
        constexpr int TI = (2*FS)/8;
        float acc = 0.f;
        const float* Wp = Vw + (size_t)(wv*TI)*NSV + o;
        const float* mp = smL + wv*TI;
        #pragma unroll 8
        for (int i = 0; i < TI; ++i) acc = fmaf(mp[i], Wp[(size_t)i*NSV], acc);
        red[wv*64 + ol] = acc;
    }
    __syncthreads();
    if (t < 64) {
        float s = Vb[o0 + t];
        #pragma unroll
        for (int g = 0; g < 8; ++g) s += red[g*64 + t];
        t1L[t] = s;
    }
    __syncthreads();

    {   // main GEMM: e_l = wv
        float acc = t1L[ol];
        const float* Ap = As + wv*KP;                    // wave-uniform base
        const float* Wp = Vw + (size_t)(2*FS)*NSV + o;
        #pragma unroll 16
        for (int i = 0; i < KP; ++i)
            acc = fmaf(Ap[i], Wp[(size_t)i*NSV], acc);
        float v = tanhf(acc);
        svOut[(size_t)(e0 + wv)*NSV + o] = v;
        red[wv*64 + ol] = v;
    }
    __syncthreads();
    if (psumOut && t < 64) {
        float s = 0.f;
        #pragma unroll
        for (int g = 0; g < 8; ++g) s += red[g*64 + t];
        psumOut[(size_t)et*NSV + o0 + t] = s;            // unscaled col sums
    }
}

// ---------------------------------------------------------------------------
// Role: pair means (layers 1..3). 32 blocks, one output per thread.
// pme[j][cc] , cc = spin*64 + c ; mean over 64 i of pIn[i][j][c].
// ---------------------------------------------------------------------------
__device__ void pmean_role(int bb, const float* __restrict__ pIn,
                           float* __restrict__ pmeOut)
{
    const int v = bb*512 + threadIdx.x;    // 0..16383
    const int j = v >> 7, cc = v & 127;
    const int spin = cc >> 6, c = cc & 63;
    const float* base = pIn + ((size_t)(spin*64)*128 + j)*64 + c;
    float s = 0.f;
    #pragma unroll 8
    for (int i = 0; i < 64; ++i) s += base[(size_t)i*8192];
    pmeOut[(size_t)j*128 + cc] = s * 0.015625f;
}

// ---------------------------------------------------------------------------
// Role: pair-stream update, layers 1/2 (FP=64). Grid-stride over 512 chunks
// of 32 pairs. W (64x64) staged once in LDS; inputs staged per chunk.
// ---------------------------------------------------------------------------
__device__ void b_role(int bb, int nb, const float* __restrict__ pIn,
                       const float* __restrict__ Ww, const float* __restrict__ Wb,
                       float* __restrict__ pOut, float* sh)
{
    float* Wl  = sh;                       // 4096
    float* inT = sh + 4096;                // 32*68
    const int t = threadIdx.x;
    for (int idx = t; idx < 4096; idx += 512) Wl[idx] = Ww[idx];
    const int oc = t & 15, o0 = oc*4, pl = t >> 4;
    const float4 wb4 = *reinterpret_cast<const float4*>(Wb + o0);
    for (int ch = bb; ch < 512; ch += nb) {
        __syncthreads();                   // protect Wl (1st iter) + inT reuse
        for (int idx = t; idx < 2048; idx += 512)
            inT[(idx>>6)*68 + (idx&63)] = pIn[(size_t)ch*2048 + idx];
        __syncthreads();
        float a0=wb4.x, a1=wb4.y, a2=wb4.z, a3=wb4.w;
        const float* a = inT + pl*68;
        #pragma unroll 8
        for (int c = 0; c < 64; ++c) {
            float av = a[c];
            float4 w = *reinterpret_cast<const float4*>(Wl + c*64 + o0);
            a0=fmaf(av,w.x,a0); a1=fmaf(av,w.y,a1);
            a2=fmaf(av,w.z,a2); a3=fmaf(av,w.w,a3);
        }
        float4 vout;
        vout.x = tanhf(a0) + a[o0+0];
        vout.y = tanhf(a1) + a[o0+1];
        vout.z = tanhf(a2) + a[o0+2];
        vout.w = tanhf(a3) + a[o0+3];
        *reinterpret_cast<float4*>(pOut + (size_t)ch*2048 + pl*64 + o0) = vout;
    }
}

// ---------------------------------------------------------------------------
// Role: layer0 pair update (FP=4, no residual). 128 blocks x 128 pairs.
// ---------------------------------------------------------------------------
__device__ void b0_role(int b, const float* __restrict__ p0,
                        const float* __restrict__ W0w, const float* __restrict__ W0b,
                        float* __restrict__ pA, float* sh)
{
    float* Wl = sh;                        // 256
    const int t = threadIdx.x;
    if (t < 256) Wl[t] = W0w[t];
    __syncthreads();
    const int o = t & 63;
    const float wb = W0b[o];
    const int plbase = (t >> 6) * 16;
    for (int g = 0; g < 16; ++g) {
        const int pair = b*128 + plbase + g;
        float4 pin = *reinterpret_cast<const float4*>(p0 + (size_t)pair*4);
        float acc = wb;
        acc = fmaf(pin.x, Wl[o],      acc);
        acc = fmaf(pin.y, Wl[64+o],   acc);
        acc = fmaf(pin.z, Wl[128+o],  acc);
        acc = fmaf(pin.w, Wl[192+o],  acc);
        pA[(size_t)pair*64 + o] = tanhf(acc);
    }
}

// ---------------------------------------------------------------------------
// Role: heads + orbital matrices, per electron (128 blocks x 512 threads).
// ---------------------------------------------------------------------------
__device__ void headsw_role(int e, const float* __restrict__ svF,
                            const float* __restrict__ vhu_w, const float* __restrict__ vhu_b,
                            const float* __restrict__ vhd_w, const float* __restrict__ vhd_b,
                            const float* __restrict__ wu_w,  const float* __restrict__ wu_b,
                            const float* __restrict__ wd_w,  const float* __restrict__ wd_b,
                            const float* __restrict__ expv,  float* __restrict__ orb,
                            float* sh)
{
    float* row  = sh;          // 512
    float* redH = sh + 512;    // 512
    float* tmpL = sh + 1024;   // 256
    const int spin = e >> 6;
    const int t = threadIdx.x;
    row[t] = svF[(size_t)e*NSV + t];
    __syncthreads();

    const float* W1 = spin ? vhd_w : vhu_w;
    const float* B1 = spin ? vhd_b : vhu_b;
    {
        const int o = t & 255, kc = t >> 8;
        float acc = kc ? 0.f : B1[o];
        const float* Wp = W1 + (size_t)(kc*256)*256 + o;
        const float* rp = row + kc*256;
        #pragma unroll 8
        for (int f = 0; f < 256; ++f)
            acc = fmaf(rp[f], Wp[(size_t)f*256], acc);
        redH[t] = acc;
    }
    __syncthreads();
    if (t < 256) tmpL[t] = redH[t] + redH[256 + t];
    __syncthreads();

    const float* W2 = spin ? wd_w : wu_w;
    const float* B2 = spin ? wd_b : wu_b;
    {
        const int o = t & 63, kc = t >> 6;
        float acc = 0.f;
        const float* Wp = W2 + (size_t)(kc*32)*64 + o;
        const float* tp = tmpL + kc*32;
        #pragma unroll
        for (int f = 0; f < 32; ++f)
            acc = fmaf(tp[f], Wp[(size_t)f*64], acc);
        redH[kc*64 + o] = acc;
    }
    __syncthreads();
    if (t < 64) {
        float s = B2[t];
        #pragma unroll
        for (int g = 0; g < 8; ++g) s += redH[g*64 + t];
        orb[(size_t)e*64 + t] = s * expv[e];
    }
}

// ---------------------------------------------------------------------------
// Role: two 64x64 log|det| via partial-pivot LU (block 0, waves 0/1).
// DPP packed argmax, bit-cast v_readlane broadcasts, deferred log.
// ---------------------------------------------------------------------------
__device__ __forceinline__ int imax2(int a, int b) { return a > b ? a : b; }
__device__ __forceinline__ float readlane_f(float x, int lane) {
    return __int_as_float(__builtin_amdgcn_readlane(__float_as_int(x), lane));
}

__device__ void det_role(const float* __restrict__ orb, float* __restrict__ out,
                         float* sh)
{
    const int t = threadIdx.x;
    if (t < 128) {
        const int w = t >> 6;
        const int lane = t & 63;
        const float* M = orb + (size_t)w*4096 + (size_t)lane*64;
        float rr[64];
        #pragma unroll
        for (int j = 0; j < 64; j += 4) {
            float4 v = *reinterpret_cast<const float4*>(M + j);
            rr[j]=v.x; rr[j+1]=v.y; rr[j+2]=v.z; rr[j+3]=v.w;
        }
        float pv_mine = 1.f;
        bool active = true;
        #pragma unroll
        for (int k = 0; k < 64; ++k) {
            int bits = (int)(__float_as_uint(rr[k]) & 0x7FFFFFC0u);
            int v = active ? (bits | lane) : lane;
            int tmp;
            tmp = __builtin_amdgcn_update_dpp(0, v, 0xB1,  0xF, 0xF, true); v = imax2(v, tmp);
            tmp = __builtin_amdgcn_update_dpp(0, v, 0x4E,  0xF, 0xF, true); v = imax2(v, tmp);
            tmp = __builtin_amdgcn_update_dpp(0, v, 0x141, 0xF, 0xF, true); v = imax2(v, tmp);
            tmp = __builtin_amdgcn_update_dpp(0, v, 0x140, 0xF, 0xF, true); v = imax2(v, tmp);
            tmp = __builtin_amdgcn_update_dpp(0, v, 0x142, 0xF, 0xF, true); v = imax2(v, tmp);
            tmp = __builtin_amdgcn_update_dpp(0, v, 0x143, 0xF, 0xF, true); v = imax2(v, tmp);
            const int idx = __builtin_amdgcn_readlane(v, 63) & 63;
            const float piv = readlane_f(rr[k], idx);
            pv_mine = (lane == k) ? piv : pv_mine;
            const float linv = __builtin_amdgcn_rcpf(piv);
            const float l = (active && lane != idx) ? rr[k]*linv : 0.f;
            if (lane == idx) active = false;
            #pragma unroll
            for (int j = k+1; j < 64; ++j)
                rr[j] = fmaf(-l, readlane_f(rr[j], idx), rr[j]);
        }
        float lg = logf(fabsf(pv_mine));
        #pragma unroll
        for (int off = 32; off; off >>= 1) lg += __shfl_down(lg, off);
        if (lane == 0) sh[w] = lg;
    }
    __syncthreads();
    if (t == 0) out[0] = sh[0] + sh[1];
}

// ---------------------------------------------------------------------------
// The single fused persistent kernel. 256 blocks x 512 threads (1 block/CU).
// ---------------------------------------------------------------------------
__global__ void __launch_bounds__(512, 2)
fused_ansatz(const float* __restrict__ r,    const float* __restrict__ apos,
             const float* __restrict__ V0w,  const float* __restrict__ V0b,
             const float* __restrict__ W0w,  const float* __restrict__ W0b,
             const float* __restrict__ V1w,  const float* __restrict__ V1b,
             const float* __restrict__ W1w,  const float* __restrict__ W1b,
             const float* __restrict__ V2w,  const float* __restrict__ V2b,
             const float* __restrict__ W2w,  const float* __restrict__ W2b,
             const float* __restrict__ afw,  const float* __restrict__ afb,
             const float* __restrict__ vhuw, const float* __restrict__ vhub,
             const float* __restrict__ vhdw, const float* __restrict__ vhdb,
             const float* __restrict__ wuw,  const float* __restrict__ wub,
             const float* __restrict__ wdw,  const float* __restrict__ wdb,
             float* __restrict__ ws, float* __restrict__ out)
{
    __shared__ float sh[6720];
    const int b = blockIdx.x;
    const int t = threadIdx.x;

    float* sv0  = ws;              // 16384
    float* p0   = sv0 + 16384;     // 65536
    float* pA   = p0  + 65536;     // 1048576
    float* pB   = pA  + 1048576;   // 1048576
    float* svA  = pB  + 1048576;   // 65536
    float* svB  = svA + 65536;     // 65536
    float* expv = svB + 65536;     // 128
    float* sm0  = expv + 128;      // 256
    float* pme0 = sm0  + 256;      // 1024
    float* pmeA = pme0 + 1024;     // 16384
    float* pmeB = pmeA + 16384;    // 16384
    float* psA  = pmeB + 16384;    // 8192
    float* psB  = psA  + 8192;     // 8192
    float* orb  = psB  + 8192;     // 8192

    // ---- P0: geometry ----
    if (b < 128) {
        const int e = b;
        const float rx = r[e*3+0], ry = r[e*3+1], rz = r[e*3+2];
        if (t < 128) {
            const int j = t;
            float dx = r[j*3+0]-rx, dy = r[j*3+1]-ry, dz = r[j*3+2]-rz;
            float len = sqrtf(dx*dx + dy*dy + dz*dz);
            if (j == e) len = 0.f;
            float* pp = p0 + ((size_t)e*128 + j)*4;
            pp[0]=dx; pp[1]=dy; pp[2]=dz; pp[3]=len;
        }
        float ex = 0.f;
        if (t >= 128 && t < 160) {
            const int a_i = t - 128;
            float dx = rx - apos[a_i*3+0], dy = ry - apos[a_i*3+1], dz = rz - apos[a_i*3+2];
            float len = sqrtf(dx*dx + dy*dy + dz*dz);
            float* sp = sv0 + (size_t)e*128 + a_i*4;
            sp[0]=dx; sp[1]=dy; sp[2]=dz; sp[3]=len;
            ex = expf(-len);
        }
        if (t >= 128 && t < 192) {       // wave 2 reduction
            #pragma unroll
            for (int off = 32; off; off >>= 1) ex += __shfl_down(ex, off);
            if (t == 128) expv[e] = ex;
        }
    }
    gsync(256);

    // ---- P1: B0 + pmean0 + smean0 ----
    if (b < 128) {
        b0_role(b, p0, W0w, W0b, pA, sh);
    } else if (b < 130) {
        const int v = (b-128)*512 + t;
        if (v < 1024) {
            const int j = v >> 3, cc = v & 7;
            const int spin = cc >> 2, c = cc & 3;
            const float* base = p0 + ((size_t)(spin*64)*128 + j)*4 + c;
            float s = 0.f;
            #pragma unroll 8
            for (int i = 0; i < 64; ++i) s += base[(size_t)i*512];
            pme0[j*8 + cc] = s * 0.015625f;
        }
    } else if (b == 130) {
        if (t < 256) {
            const int col = t & 127, i0 = (t >> 7) * 64;
            const float* base = sv0 + (size_t)i0*128 + col;
            float s = 0.f;
            #pragma unroll 8
            for (int i = 0; i < 64; ++i) s += base[(size_t)i*128];
            sm0[t] = s * 0.015625f;
        }
    }
    gsync(512);

    // ---- P2: A0 | pmean1 | B1 ----
    if (b < 128)       a_role<128, 4, true >(b, sv0, pme0, sm0, V0w, V0b, svA, psA, sh);
    else if (b < 160)  pmean_role(b-128, pA, pmeA);
    else               b_role(b-160, 96, pA, W1w, W1b, pB, sh);
    gsync(768);

    // ---- P3: A1 | pmean2 | B2 ----
    if (b < 128)       a_role<512, 64, false>(b, svA, pmeA, psA, V1w, V1b, svB, psB, sh);
    else if (b < 160)  pmean_role(b-128, pB, pmeB);
    else               b_role(b-160, 96, pB, W2w, W2b, pA, sh);
    gsync(1024);

    // ---- P4: A2 | pmean3 ----
    if (b < 128)       a_role<512, 64, false>(b, svB, pmeB, psB, V2w, V2b, svA, psA, sh);
    else if (b < 160)  pmean_role(b-128, pA, pmeA);
    gsync(1280);

    // ---- P5: A3 (after-layer) ----
    if (b < 128)       a_role<512, 64, false>(b, svA, pmeA, psA, afw, afb, svB, nullptr, sh);
    gsync(1536);

    // ---- P6: heads + sw ----
    if (b < 128)
        headsw_role(b, svB, vhuw, vhub, vhdw, vhdb, wuw, wub, wdw, wdb, expv, orb, sh);
    gsync(1792);

    // ---- P7: det ----
    if (b == 0) det_role(orb, out, sh);

    // ---- exit protocol: reset barrier state for the next launch ----
    __syncthreads();
    if (t == 0) {
        __threadfence();
        atomicAdd(&g_exit, 1u);
        if (b == 0) {
            while (__hip_atomic_load(&g_exit, __ATOMIC_ACQUIRE,
                                     __HIP_MEMORY_SCOPE_AGENT) < 256u)
                __builtin_amdgcn_s_sleep(2);
            atomicExch(&g_bar,  0u);
            atomicExch(&g_exit, 0u);
        }
    }
}

// ---------------------------------------------------------------------------
extern "C" void kernel_launch(void* const* d_in, const int* in_sizes, int n_in,
                              void* d_out, int out_size, void* d_ws, size_t ws_size,
                              hipStream_t stream)
{
    const float* r    = (const float*)d_in[0];
    const float* apos = (const float*)d_in[1];
    const float* V0w  = (const float*)d_in[2];
    const float* V0b  = (const float*)d_in[3];
    const float* W0w  = (const float*)d_in[4];
    const float* W0b  = (const float*)d_in[5];
    const float* V1w  = (const float*)d_in[6];
    const float* V1b  = (const float*)d_in[7];
    const float* W1w  = (const float*)d_in[8];
    const float* W1b  = (const float*)d_in[9];
    const float* V2w  = (const float*)d_in[10];
    const float* V2b  = (const float*)d_in[11];
    const float* W2w  = (const float*)d_in[12];
    const float* W2b  = (const float*)d_in[13];
    const float* afw  = (const float*)d_in[14];
    const float* afb  = (const float*)d_in[15];
    const float* vhuw = (const float*)d_in[16];
    const float* vhub = (const float*)d_in[17];
    const float* vhdw = (const float*)d_in[18];
    const float* vhdb = (const float*)d_in[19];
    const float* wuw  = (const float*)d_in[20];
    const float* wub  = (const float*)d_in[21];
    const float* wdw  = (const float*)d_in[22];
    const float* wdb  = (const float*)d_in[23];

    fused_ansatz<<<dim3(256), dim3(512), 0, stream>>>(
        r, apos, V0w, V0b, W0w, W0b, V1w, V1b, W1w, W1b,
        V2w, V2b, W2w, W2b, afw, afb, vhuw, vhub, vhdw, vhdb,
        wuw, wub, wdw, wdb, (float*)d_ws, (float*)d_out);
}

// Round 6
// 171.631 us; speedup vs baseline: 4.8922x; 4.8922x over previous
//
#include <hip/hip_runtime.h>
#include <math.h>

#define NSV 512

// ---------------------------------------------------------------------------
// Persistent-kernel grid barrier, v2.
// All cross-block data moves via RELAXED+AGENT atomic accesses (sc0/sc1 bits:
// device-coherent per-access, served by the coherent point) -> the barrier
// needs NO cache-wide fences. R5's __threadfence + ACQUIRE poll emitted
// buffer_wbl2/buffer_inv per iteration, nuking the per-XCD L2s (852us).
// __syncthreads() drains vmcnt for every wave (compiler emits s_waitcnt
// vmcnt(0) before s_barrier), so arrival implies this block's sc1 stores
// have reached the coherent point.
// ---------------------------------------------------------------------------
__device__ unsigned g_bar  = 0;
__device__ unsigned g_exit = 0;

__device__ __forceinline__ float gload(const float* p) {
    return __hip_atomic_load(p, __ATOMIC_RELAXED, __HIP_MEMORY_SCOPE_AGENT);
}
__device__ __forceinline__ void gstore(float* p, float v) {
    __hip_atomic_store(p, v, __ATOMIC_RELAXED, __HIP_MEMORY_SCOPE_AGENT);
}

__device__ __forceinline__ void gsync(unsigned target) {
    asm volatile("s_waitcnt vmcnt(0)" ::: "memory");   // belt & braces per-wave
    __syncthreads();
    if (threadIdx.x == 0) {
        atomicAdd(&g_bar, 1u);                          // relaxed device atomic
        while (__hip_atomic_load(&g_bar, __ATOMIC_RELAXED,
                                 __HIP_MEMORY_SCOPE_AGENT) < target)
            __builtin_amdgcn_s_sleep(4);
    }
    __syncthreads();
}

// ---------------------------------------------------------------------------
// A role: s-stream GEMM. 128 blocks, tile 8e x 64o (et=b>>3, ot=b&7).
// smean computed in-block: L0 from sv0 (64-row sums), else from psum tiles.
// ---------------------------------------------------------------------------
template<int FS, int FP, bool L0>
__device__ void a_role(int b, const float* __restrict__ svIn,
                       const float* __restrict__ pmeIn,
                       const float* __restrict__ smSrc,
                       const float* __restrict__ Vw, const float* __restrict__ Vb,
                       float* __restrict__ svOut, float* __restrict__ psumOut,
                       float* sh)
{
    constexpr int KP = 2*FP + FS;          // 136 (L0) or 640
    const int t  = threadIdx.x;
    const int et = b >> 3, ot = b & 7;
    const int e0 = et * 8;
    const int o0 = ot * 64;
    const int ol = t & 63;
    const int o  = o0 + ol;
    const int wv = t >> 6;                 // 0..7
    float* As  = sh;                       // 8*KP
    float* smL = As + 8*KP;                // 2*FS
    float* red = smL + 2*FS;               // 512
    float* t1L = red + 512;                // 64

    for (int idx = t; idx < 8*2*FP; idx += 512)
        As[(idx/(2*FP))*KP + idx%(2*FP)] =
            gload(&pmeIn[(size_t)(e0 + idx/(2*FP))*(2*FP) + idx%(2*FP)]);
    for (int idx = t; idx < 8*FS; idx += 512)
        As[(idx/FS)*KP + 2*FP + idx%FS] =
            gload(&svIn[(size_t)(e0 + idx/FS)*FS + idx%FS]);
    if (L0) {
        for (int idx = t; idx < 2*FS; idx += 512) {   // 256 sums, 64-deep
            const int col = (idx < FS) ? idx : idx - FS;
            const int i0  = (idx < FS) ? 0 : 64;
            float s = 0.f;
            #pragma unroll 8
            for (int i = 0; i < 64; ++i)
                s += gload(&smSrc[(size_t)(i0+i)*FS + col]);
            smL[idx] = s * 0.015625f;
        }
    } else {
        for (int idx = t; idx < 2*FS; idx += 512) {   // 1024 sums over psum tiles
            const int col = (idx < FS) ? idx : idx - FS;
            const int r0  = (idx < FS) ? 0 : 8;
            float s = 0.f;
            #pragma unroll
            for (int k2 = 0; k2 < 8; ++k2)
                s += gload(&smSrc[(size_t)(r0+k2)*NSV + col]);
            smL[idx] = s * 0.015625f;
        }
    }
    __syncthreads();

    {   // t1 partials: K = 2*FS over the 8 waves
        constexpr int TI = (2*FS)/8;
        float acc = 0.f;
        const float* Wp = Vw + (size_t)(wv*TI)*NSV + o;
        const float* mp = smL + wv*TI;
        #pragma unroll 8
        for (int i = 0; i < TI; ++i) acc = fmaf(mp[i], Wp[(size_t)i*NSV], acc);
        red[wv*64 + ol] = acc;
    }
    __syncthreads();
    if (t < 64) {
        float s = Vb[o0 + t];
        #pragma unroll
        for (int g = 0; g < 8; ++g) s += red[g*64 + t];
        t1L[t] = s;
    }
    __syncthreads();

    {   // main GEMM: e_l = wv
        float acc = t1L[ol];
        const float* Ap = As + wv*KP;                    // wave-uniform base
        const float* Wp = Vw + (size_t)(2*FS)*NSV + o;
        #pragma unroll 16
        for (int i = 0; i < KP; ++i)
            acc = fmaf(Ap[i], Wp[(size_t)i*NSV], acc);
        float v = tanhf(acc);
        gstore(&svOut[(size_t)(e0 + wv)*NSV + o], v);
        red[wv*64 + ol] = v;
    }
    __syncthreads();
    if (psumOut && t < 64) {
        float s = 0.f;
        #pragma unroll
        for (int g = 0; g < 8; ++g) s += red[g*64 + t];
        gstore(&psumOut[(size_t)et*NSV + o0 + t], s);    // unscaled col sums
    }
}

// ---------------------------------------------------------------------------
// pmean role: 32 blocks, one (j,cc) output per thread, 64-deep strided sums.
// ---------------------------------------------------------------------------
__device__ void pmean_role(int bb, const float* __restrict__ pIn,
                           float* __restrict__ pmeOut)
{
    const int v = bb*512 + threadIdx.x;    // 0..16383
    const int j = v >> 7, cc = v & 127;
    const int spin = cc >> 6, c = cc & 63;
    const float* base = pIn + ((size_t)(spin*64)*128 + j)*64 + c;
    float s = 0.f;
    #pragma unroll 8
    for (int i = 0; i < 64; ++i) s += gload(&base[(size_t)i*8192]);
    gstore(&pmeOut[(size_t)j*128 + cc], s * 0.015625f);
}

// ---------------------------------------------------------------------------
// B role: pair update (FP=64, +residual). 96 blocks grid-stride 512 chunks.
// ---------------------------------------------------------------------------
__device__ void b_role(int bb, int nb, const float* __restrict__ pIn,
                       const float* __restrict__ Ww, const float* __restrict__ Wb,
                       float* __restrict__ pOut, float* sh)
{
    float* Wl  = sh;                       // 4096
    float* inT = sh + 4096;                // 32*68
    const int t = threadIdx.x;
    for (int idx = t; idx < 4096; idx += 512) Wl[idx] = Ww[idx];
    const int oc = t & 15, o0 = oc*4, pl = t >> 4;
    const float4 wb4 = *reinterpret_cast<const float4*>(Wb + o0);
    for (int ch = bb; ch < 512; ch += nb) {
        __syncthreads();                   // protect Wl (1st iter) + inT reuse
        for (int idx = t; idx < 2048; idx += 512)
            inT[(idx>>6)*68 + (idx&63)] = gload(&pIn[(size_t)ch*2048 + idx]);
        __syncthreads();
        float a0=wb4.x, a1=wb4.y, a2=wb4.z, a3=wb4.w;
        const float* a = inT + pl*68;
        #pragma unroll 8
        for (int c = 0; c < 64; ++c) {
            float av = a[c];
            float4 w = *reinterpret_cast<const float4*>(Wl + c*64 + o0);
            a0=fmaf(av,w.x,a0); a1=fmaf(av,w.y,a1);
            a2=fmaf(av,w.z,a2); a3=fmaf(av,w.w,a3);
        }
        float* op = pOut + (size_t)ch*2048 + pl*64 + o0;
        gstore(op+0, tanhf(a0) + a[o0+0]);
        gstore(op+1, tanhf(a1) + a[o0+1]);
        gstore(op+2, tanhf(a2) + a[o0+2]);
        gstore(op+3, tanhf(a3) + a[o0+3]);
    }
}

// ---------------------------------------------------------------------------
// heads + orbital matrices, per electron.
// ---------------------------------------------------------------------------
__device__ void headsw_role(int e, const float* __restrict__ svF,
                            const float* __restrict__ vhu_w, const float* __restrict__ vhu_b,
                            const float* __restrict__ vhd_w, const float* __restrict__ vhd_b,
                            const float* __restrict__ wu_w,  const float* __restrict__ wu_b,
                            const float* __restrict__ wd_w,  const float* __restrict__ wd_b,
                            const float* __restrict__ expv,  float* __restrict__ orb,
                            float* sh)
{
    float* row  = sh;          // 512
    float* redH = sh + 512;    // 512
    float* tmpL = sh + 1024;   // 256
    const int spin = e >> 6;
    const int t = threadIdx.x;
    row[t] = gload(&svF[(size_t)e*NSV + t]);
    __syncthreads();

    const float* W1 = spin ? vhd_w : vhu_w;
    const float* B1 = spin ? vhd_b : vhu_b;
    {
        const int o = t & 255, kc = t >> 8;
        float acc = kc ? 0.f : B1[o];
        const float* Wp = W1 + (size_t)(kc*256)*256 + o;
        const float* rp = row + kc*256;
        #pragma unroll 8
        for (int f = 0; f < 256; ++f)
            acc = fmaf(rp[f], Wp[(size_t)f*256], acc);
        redH[t] = acc;
    }
    __syncthreads();
    if (t < 256) tmpL[t] = redH[t] + redH[256 + t];
    __syncthreads();

    const float* W2 = spin ? wd_w : wu_w;
    const float* B2 = spin ? wd_b : wu_b;
    {
        const int o = t & 63, kc = t >> 6;
        float acc = 0.f;
        const float* Wp = W2 + (size_t)(kc*32)*64 + o;
        const float* tp = tmpL + kc*32;
        #pragma unroll
        for (int f = 0; f < 32; ++f)
            acc = fmaf(tp[f], Wp[(size_t)f*64], acc);
        redH[kc*64 + o] = acc;
    }
    __syncthreads();
    if (t < 64) {
        float s = B2[t];
        #pragma unroll
        for (int g = 0; g < 8; ++g) s += redH[g*64 + t];
        orb[(size_t)e*64 + t] = s * gload(&expv[e]);   // plain store: det is a
    }                                                   // separate dispatch
}

// ---------------------------------------------------------------------------
// Fused persistent kernel: 256 blocks x 512 threads, 6 phases, 5 barriers.
// ---------------------------------------------------------------------------
__global__ void __launch_bounds__(512)
fused_ansatz(const float* __restrict__ r,    const float* __restrict__ apos,
             const float* __restrict__ V0w,  const float* __restrict__ V0b,
             const float* __restrict__ W0w,  const float* __restrict__ W0b,
             const float* __restrict__ V1w,  const float* __restrict__ V1b,
             const float* __restrict__ W1w,  const float* __restrict__ W1b,
             const float* __restrict__ V2w,  const float* __restrict__ V2b,
             const float* __restrict__ W2w,  const float* __restrict__ W2b,
             const float* __restrict__ afw,  const float* __restrict__ afb,
             const float* __restrict__ vhuw, const float* __restrict__ vhub,
             const float* __restrict__ vhdw, const float* __restrict__ vhdb,
             const float* __restrict__ wuw,  const float* __restrict__ wub,
             const float* __restrict__ wdw,  const float* __restrict__ wdb,
             float* __restrict__ ws)
{
    __shared__ float sh[6720];
    const int b = blockIdx.x;
    const int t = threadIdx.x;

    float* sv0  = ws;              // 16384
    float* pA   = sv0 + 16384;     // 1048576
    float* pB   = pA  + 1048576;   // 1048576
    float* svA  = pB  + 1048576;   // 65536
    float* svB  = svA + 65536;     // 65536
    float* expv = svB + 65536;     // 128
    float* pme0 = expv + 128;      // 1024
    float* pmeA = pme0 + 1024;     // 16384
    float* pmeB = pmeA + 16384;    // 16384
    float* psA  = pmeB + 16384;    // 8192
    float* psB  = psA  + 8192;     // 8192
    float* orb  = psB  + 8192;     // 8192

    // ---- P0: geometry + layer0 pair-update + pme0 (all from r alone) ----
    if (b < 128) {
        float* pr   = sh;          // 128 pairs x 4 (this block's p0 row)
        float* W0l  = sh + 512;    // 256
        float* shex = sh + 768;    // 32
        const float rx = r[b*3+0], ry = r[b*3+1], rz = r[b*3+2];
        if (t < 128) {
            const int j = t;
            float dx = r[j*3+0]-rx, dy = r[j*3+1]-ry, dz = r[j*3+2]-rz;
            float len = (j == b) ? 0.f : sqrtf(dx*dx + dy*dy + dz*dz);
            pr[j*4+0]=dx; pr[j*4+1]=dy; pr[j*4+2]=dz; pr[j*4+3]=len;
        } else if (t < 384) {
            W0l[t-128] = W0w[t-128];
        } else if (t < 416) {
            const int a_i = t - 384;
            float dx = rx-apos[a_i*3+0], dy = ry-apos[a_i*3+1], dz = rz-apos[a_i*3+2];
            float len = sqrtf(dx*dx + dy*dy + dz*dz);
            gstore(&sv0[(size_t)b*128 + a_i*4 + 0], dx);
            gstore(&sv0[(size_t)b*128 + a_i*4 + 1], dy);
            gstore(&sv0[(size_t)b*128 + a_i*4 + 2], dz);
            gstore(&sv0[(size_t)b*128 + a_i*4 + 3], len);
            shex[a_i] = expf(-len);
        }
        __syncthreads();
        // layer0 pair update: 128 pairs x 64 outs, K=4, from LDS
        {
            const int o = t & 63;
            const int p0i = (t >> 6) * 16;
            const float wb = W0b[o];
            const float w0 = W0l[o], w1 = W0l[64+o], w2 = W0l[128+o], w3 = W0l[192+o];
            for (int g = 0; g < 16; ++g) {
                const int pair = p0i + g;
                const float* pp = pr + pair*4;
                float acc = wb;
                acc = fmaf(pp[0], w0, acc); acc = fmaf(pp[1], w1, acc);
                acc = fmaf(pp[2], w2, acc); acc = fmaf(pp[3], w3, acc);
                gstore(&pA[((size_t)b*128 + pair)*64 + o], tanhf(acc));
            }
        }
        // pme0[b][cc]: column-b means need p0[i][b] = -p0[b][i].xyz, same len
        if (t < 8) {
            const int spin = t >> 2, c = t & 3, i0 = spin*64;
            float s = 0.f;
            #pragma unroll 8
            for (int i = 0; i < 64; ++i) s += pr[(i0+i)*4 + c];
            float m = s * 0.015625f;
            if (c < 3) m = -m;
            gstore(&pme0[b*8 + t], m);
        }
        if (t == 0) {
            float s = 0.f;
            #pragma unroll 8
            for (int i = 0; i < 32; ++i) s += shex[i];
            gstore(&expv[b], s);
        }
    }
    gsync(256);

    // ---- P1: A0 | pmean1(pA) | B1(pA->pB) ----
    if (b < 128)       a_role<128, 4, true >(b, sv0, pme0, sv0, V0w, V0b, svA, psA, sh);
    else if (b < 160)  pmean_role(b-128, pA, pmeA);
    else               b_role(b-160, 96, pA, W1w, W1b, pB, sh);
    gsync(512);

    // ---- P2: A1 | pmean2(pB) | B2(pB->pA) ----
    if (b < 128)       a_role<512, 64, false>(b, svA, pmeA, psA, V1w, V1b, svB, psB, sh);
    else if (b < 160)  pmean_role(b-128, pB, pmeB);
    else               b_role(b-160, 96, pB, W2w, W2b, pA, sh);
    gsync(768);

    // ---- P3: A2 | pmean3(pA) ----
    if (b < 128)       a_role<512, 64, false>(b, svB, pmeB, psB, V2w, V2b, svA, psA, sh);
    else if (b < 160)  pmean_role(b-128, pA, pmeA);
    gsync(1024);

    // ---- P4: A3 (after-layer) ----
    if (b < 128)       a_role<512, 64, false>(b, svA, pmeA, psA, afw, afb, svB, nullptr, sh);
    gsync(1280);

    // ---- P5: heads + sw ----
    if (b < 128)
        headsw_role(b, svB, vhuw, vhub, vhdw, vhdb, wuw, wub, wdw, wdb, expv, orb, sh);

    // ---- exit protocol: reset barrier state for the next replay ----
    __syncthreads();
    if (t == 0) {
        atomicAdd(&g_exit, 1u);
        if (b == 0) {
            while (__hip_atomic_load(&g_exit, __ATOMIC_RELAXED,
                                     __HIP_MEMORY_SCOPE_AGENT) < 256u)
                __builtin_amdgcn_s_sleep(4);
            atomicExch(&g_bar,  0u);
            atomicExch(&g_exit, 0u);
        }
    }
}

// ---------------------------------------------------------------------------
// det: two 64x64 log|det| via partial-pivot LU (own dispatch: keeps rr[64]
// in registers, ~72 VGPR). DPP packed argmax, bit-cast readlane, deferred log.
// ---------------------------------------------------------------------------
__device__ __forceinline__ int imax2(int a, int b) { return a > b ? a : b; }
__device__ __forceinline__ float readlane_f(float x, int lane) {
    return __int_as_float(__builtin_amdgcn_readlane(__float_as_int(x), lane));
}

__global__ __launch_bounds__(128)
void det_kernel(const float* __restrict__ ws, float* __restrict__ out)
{
    const float* orb = ws + 16384 + 2*1048576 + 2*65536 + 128 + 1024 + 2*16384 + 2*8192;
    __shared__ float parts[2];
    const int t = threadIdx.x;
    const int w = t >> 6;
    const int lane = t & 63;
    const float* M = orb + (size_t)w*4096 + (size_t)lane*64;
    float rr[64];
    #pragma unroll
    for (int j = 0; j < 64; j += 4) {
        float4 v = *reinterpret_cast<const float4*>(M + j);
        rr[j]=v.x; rr[j+1]=v.y; rr[j+2]=v.z; rr[j+3]=v.w;
    }
    float pv_mine = 1.f;
    bool active = true;
    #pragma unroll
    for (int k = 0; k < 64; ++k) {
        int bits = (int)(__float_as_uint(rr[k]) & 0x7FFFFFC0u);
        int v = active ? (bits | lane) : lane;
        int tmp;
        tmp = __builtin_amdgcn_update_dpp(0, v, 0xB1,  0xF, 0xF, true); v = imax2(v, tmp);
        tmp = __builtin_amdgcn_update_dpp(0, v, 0x4E,  0xF, 0xF, true); v = imax2(v, tmp);
        tmp = __builtin_amdgcn_update_dpp(0, v, 0x141, 0xF, 0xF, true); v = imax2(v, tmp);
        tmp = __builtin_amdgcn_update_dpp(0, v, 0x140, 0xF, 0xF, true); v = imax2(v, tmp);
        tmp = __builtin_amdgcn_update_dpp(0, v, 0x142, 0xF, 0xF, true); v = imax2(v, tmp);
        tmp = __builtin_amdgcn_update_dpp(0, v, 0x143, 0xF, 0xF, true); v = imax2(v, tmp);
        const int idx = __builtin_amdgcn_readlane(v, 63) & 63;
        const float piv = readlane_f(rr[k], idx);
        pv_mine = (lane == k) ? piv : pv_mine;
        const float linv = __builtin_amdgcn_rcpf(piv);
        const float l = (active && lane != idx) ? rr[k]*linv : 0.f;
        if (lane == idx) active = false;
        #pragma unroll
        for (int j = k+1; j < 64; ++j)
            rr[j] = fmaf(-l, readlane_f(rr[j], idx), rr[j]);
    }
    float lg = logf(fabsf(pv_mine));
    #pragma unroll
    for (int off = 32; off; off >>= 1) lg += __shfl_down(lg, off);
    if (lane == 0) parts[w] = lg;
    __syncthreads();
    if (t == 0) out[0] = parts[0] + parts[1];
}

// ---------------------------------------------------------------------------
extern "C" void kernel_launch(void* const* d_in, const int* in_sizes, int n_in,
                              void* d_out, int out_size, void* d_ws, size_t ws_size,
                              hipStream_t stream)
{
    const float* r    = (const float*)d_in[0];
    const float* apos = (const float*)d_in[1];
    const float* V0w  = (const float*)d_in[2];
    const float* V0b  = (const float*)d_in[3];
    const float* W0w  = (const float*)d_in[4];
    const float* W0b  = (const float*)d_in[5];
    const float* V1w  = (const float*)d_in[6];
    const float* V1b  = (const float*)d_in[7];
    const float* W1w  = (const float*)d_in[8];
    const float* W1b  = (const float*)d_in[9];
    const float* V2w  = (const float*)d_in[10];
    const float* V2b  = (const float*)d_in[11];
    const float* W2w  = (const float*)d_in[12];
    const float* W2b  = (const float*)d_in[13];
    const float* afw  = (const float*)d_in[14];
    const float* afb  = (const float*)d_in[15];
    const float* vhuw = (const float*)d_in[16];
    const float* vhub = (const float*)d_in[17];
    const float* vhdw = (const float*)d_in[18];
    const float* vhdb = (const float*)d_in[19];
    const float* wuw  = (const float*)d_in[20];
    const float* wub  = (const float*)d_in[21];
    const float* wdw  = (const float*)d_in[22];
    const float* wdb  = (const float*)d_in[23];

    fused_ansatz<<<dim3(256), dim3(512), 0, stream>>>(
        r, apos, V0w, V0b, W0w, W0b, V1w, V1b, W1w, W1b,
        V2w, V2b, W2w, W2b, afw, afb, vhuw, vhub, vhdw, vhdb,
        wuw, wub, wdw, wdb, (float*)d_ws);
    det_kernel<<<1, 128, 0, stream>>>((const float*)d_ws, (float*)d_out);
}

// Round 7
// 98.249 us; speedup vs baseline: 8.5462x; 1.7469x over previous
//
#include <hip/hip_runtime.h>
#include <math.h>

#define NSV 512

// ---------------------------------------------------------------------------
// K1: pchain — the ENTIRE pair stream, one block per column j, fully in LDS.
// p[i][j] chain: p0 (4) -> tanh(@W0+b0) (64) -> +res tanh(@W1+b1) -> +res
// tanh(@W2+b2). Emits ONLY the per-layer spin means pme0..pme3 (+ sv0, expv).
// The p tensor never touches global memory.
// ---------------------------------------------------------------------------
__global__ __launch_bounds__(512)
void pchain_kernel(const float* __restrict__ r, const float* __restrict__ apos,
                   const float* __restrict__ W0w, const float* __restrict__ W0b,
                   const float* __restrict__ W1w, const float* __restrict__ W1b,
                   const float* __restrict__ W2w, const float* __restrict__ W2b,
                   float* __restrict__ sv0, float* __restrict__ expv,
                   float* __restrict__ pme0, float* __restrict__ pme1,
                   float* __restrict__ pme2, float* __restrict__ pme3)
{
    __shared__ float rL[384];
    __shared__ float W0l[256];
    __shared__ float shex[32];
    __shared__ __align__(16) float p0c[512];       // column j raw features
    __shared__ __align__(16) float PA[128*68];     // current p values (padded)
    __shared__ __align__(16) float Wbuf[4096];     // W1 then W2
    const int j = blockIdx.x;
    const int t = threadIdx.x;
    const int i  = t >> 2;                         // pair row 0..127
    const int oc = t & 3;
    const int o0 = oc * 16;

    if (t < 384) rL[t] = r[t];
    for (int idx = t; idx < 4096; idx += 512) Wbuf[idx] = W1w[idx];
    if (t < 256) W0l[t] = W0w[t];
    __syncthreads();

    const float rjx = rL[j*3+0], rjy = rL[j*3+1], rjz = rL[j*3+2];
    if (t < 128) {   // p0[i][j] = r[j]-r[i], len (0 on diag)
        const int ii = t;
        float dx = rjx - rL[ii*3+0], dy = rjy - rL[ii*3+1], dz = rjz - rL[ii*3+2];
        float len = (ii == j) ? 0.f : sqrtf(dx*dx + dy*dy + dz*dz);
        p0c[ii*4+0]=dx; p0c[ii*4+1]=dy; p0c[ii*4+2]=dz; p0c[ii*4+3]=len;
    } else if (t < 160) {   // sv0 row j + exp terms
        const int k = t - 128;
        float dx = rjx - apos[k*3+0], dy = rjy - apos[k*3+1], dz = rjz - apos[k*3+2];
        float len = sqrtf(dx*dx + dy*dy + dz*dz);
        float* sp = sv0 + (size_t)j*128 + k*4;
        sp[0]=dx; sp[1]=dy; sp[2]=dz; sp[3]=len;
        shex[k] = expf(-len);
    }
    __syncthreads();

    // layer0: PA[i][o] = tanh(p0c[i] @ W0 + b0); also pme0 + expv
    {
        const float x0=p0c[i*4+0], x1=p0c[i*4+1], x2=p0c[i*4+2], x3=p0c[i*4+3];
        #pragma unroll
        for (int k = 0; k < 16; ++k) {
            const int o = o0 + k;
            float acc = W0b[o];
            acc = fmaf(x0, W0l[o],     acc);
            acc = fmaf(x1, W0l[64+o],  acc);
            acc = fmaf(x2, W0l[128+o], acc);
            acc = fmaf(x3, W0l[192+o], acc);
            PA[i*68+o] = tanhf(acc);
        }
    }
    if (t < 8) {
        const int spin = t >> 2, c = t & 3;
        float s = 0.f;
        #pragma unroll 8
        for (int k = 0; k < 64; ++k) s += p0c[(spin*64+k)*4 + c];
        pme0[j*8 + t] = s * 0.015625f;
    }
    if (t == 8) {
        float s = 0.f;
        #pragma unroll 8
        for (int k = 0; k < 32; ++k) s += shex[k];
        expv[j] = s;
    }
    __syncthreads();

    // pme1 (reads PA) + layer1 compute (reads PA, Wbuf=W1); write after barrier
    if (t < 128) {
        const int spin = t >> 6, c = t & 63;
        float s = 0.f;
        #pragma unroll 8
        for (int k = 0; k < 64; ++k) s += PA[(spin*64+k)*68 + c];
        pme1[j*128 + t] = s * 0.015625f;
    }
    float acc[16], res[16];
    const float* pa = PA + i*68;
    {
        #pragma unroll
        for (int k = 0; k < 16; ++k) acc[k] = W1b[o0+k];
        #pragma unroll 4
        for (int c = 0; c < 64; ++c) {
            const float av = pa[c];
            const float* wr = Wbuf + c*64 + o0;
            float4 wa = *reinterpret_cast<const float4*>(wr);
            float4 wb = *reinterpret_cast<const float4*>(wr+4);
            float4 wc = *reinterpret_cast<const float4*>(wr+8);
            float4 wd = *reinterpret_cast<const float4*>(wr+12);
            acc[0] =fmaf(av,wa.x,acc[0]);  acc[1] =fmaf(av,wa.y,acc[1]);
            acc[2] =fmaf(av,wa.z,acc[2]);  acc[3] =fmaf(av,wa.w,acc[3]);
            acc[4] =fmaf(av,wb.x,acc[4]);  acc[5] =fmaf(av,wb.y,acc[5]);
            acc[6] =fmaf(av,wb.z,acc[6]);  acc[7] =fmaf(av,wb.w,acc[7]);
            acc[8] =fmaf(av,wc.x,acc[8]);  acc[9] =fmaf(av,wc.y,acc[9]);
            acc[10]=fmaf(av,wc.z,acc[10]); acc[11]=fmaf(av,wc.w,acc[11]);
            acc[12]=fmaf(av,wd.x,acc[12]); acc[13]=fmaf(av,wd.y,acc[13]);
            acc[14]=fmaf(av,wd.z,acc[14]); acc[15]=fmaf(av,wd.w,acc[15]);
        }
        #pragma unroll
        for (int k = 0; k < 16; ++k) res[k] = pa[o0+k];
    }
    __syncthreads();
    #pragma unroll
    for (int k = 0; k < 16; ++k) PA[i*68+o0+k] = tanhf(acc[k]) + res[k];
    __syncthreads();

    // pme2 (reads PA) + restage Wbuf = W2
    if (t < 128) {
        const int spin = t >> 6, c = t & 63;
        float s = 0.f;
        #pragma unroll 8
        for (int k = 0; k < 64; ++k) s += PA[(spin*64+k)*68 + c];
        pme2[j*128 + t] = s * 0.015625f;
    }
    for (int idx = t; idx < 4096; idx += 512) Wbuf[idx] = W2w[idx];
    __syncthreads();

    // layer2 compute; write after barrier
    {
        #pragma unroll
        for (int k = 0; k < 16; ++k) acc[k] = W2b[o0+k];
        #pragma unroll 4
        for (int c = 0; c < 64; ++c) {
            const float av = pa[c];
            const float* wr = Wbuf + c*64 + o0;
            float4 wa = *reinterpret_cast<const float4*>(wr);
            float4 wb = *reinterpret_cast<const float4*>(wr+4);
            float4 wc = *reinterpret_cast<const float4*>(wr+8);
            float4 wd = *reinterpret_cast<const float4*>(wr+12);
            acc[0] =fmaf(av,wa.x,acc[0]);  acc[1] =fmaf(av,wa.y,acc[1]);
            acc[2] =fmaf(av,wa.z,acc[2]);  acc[3] =fmaf(av,wa.w,acc[3]);
            acc[4] =fmaf(av,wb.x,acc[4]);  acc[5] =fmaf(av,wb.y,acc[5]);
            acc[6] =fmaf(av,wb.z,acc[6]);  acc[7] =fmaf(av,wb.w,acc[7]);
            acc[8] =fmaf(av,wc.x,acc[8]);  acc[9] =fmaf(av,wc.y,acc[9]);
            acc[10]=fmaf(av,wc.z,acc[10]); acc[11]=fmaf(av,wc.w,acc[11]);
            acc[12]=fmaf(av,wd.x,acc[12]); acc[13]=fmaf(av,wd.y,acc[13]);
            acc[14]=fmaf(av,wd.z,acc[14]); acc[15]=fmaf(av,wd.w,acc[15]);
        }
        #pragma unroll
        for (int k = 0; k < 16; ++k) res[k] = pa[o0+k];
    }
    __syncthreads();
    #pragma unroll
    for (int k = 0; k < 16; ++k) PA[i*68+o0+k] = tanhf(acc[k]) + res[k];
    __syncthreads();

    if (t < 128) {
        const int spin = t >> 6, c = t & 63;
        float s = 0.f;
        #pragma unroll 8
        for (int k = 0; k < 64; ++k) s += PA[(spin*64+k)*68 + c];
        pme3[j*128 + t] = s * 0.015625f;
    }
}

// ---------------------------------------------------------------------------
// A kernel: s-stream GEMM. 256 blocks x 512 threads, tile 4e x 64o.
// et=b>>3 (0..31), ot=b&7 -> XCD==ot (default round-robin) so the 32 blocks
// sharing an o-tile share weight columns in one XCD L2.
// smean: L0 from sv0 columns; else from psum tiles (16 rows per spin).
// Emits psumOut[et][o] = per-block column sums for the NEXT layer's smean.
// ---------------------------------------------------------------------------
template<int FS, int FP, bool L0>
__global__ __launch_bounds__(512)
void a2_kernel(const float* __restrict__ svIn, const float* __restrict__ pmeIn,
               const float* __restrict__ psumIn,
               const float* __restrict__ Vw, const float* __restrict__ Vb,
               float* __restrict__ svOut, float* __restrict__ psumOut)
{
    constexpr int KP  = 2*FP + FS;        // 136 (L0) or 640
    constexpr int KP2 = KP/2;
    __shared__ __align__(16) float As[4*KP];
    __shared__ __align__(16) float smL[2*FS];
    __shared__ __align__(16) float red[512];
    __shared__ float t1L[64];
    const int t  = threadIdx.x;
    const int et = blockIdx.x >> 3;
    const int e0 = et * 4;
    const int o0 = (blockIdx.x & 7) * 64;
    const int ol = t & 63;
    const int o  = o0 + ol;
    const int wv = t >> 6;                // 0..7

    for (int idx = t; idx < 4*2*FP; idx += 512)
        As[(idx/(2*FP))*KP + idx%(2*FP)] =
            pmeIn[(size_t)(e0 + idx/(2*FP))*(2*FP) + idx%(2*FP)];
    for (int idx = t; idx < FS; idx += 512) {     // 4 rows x FS/4 float4s
        const int row = idx / (FS/4), c4 = idx % (FS/4);
        *reinterpret_cast<float4*>(&As[row*KP + 2*FP + c4*4]) =
            *reinterpret_cast<const float4*>(&svIn[(size_t)(e0+row)*FS + c4*4]);
    }
    if (L0) {
        for (int idx = t; idx < 2*FS; idx += 512) {
            const int col = (idx < FS) ? idx : idx - FS;
            const int i0  = (idx < FS) ? 0 : 64;
            const float* base = svIn + (size_t)i0*FS + col;
            float s = 0.f;
            #pragma unroll 8
            for (int k = 0; k < 64; ++k) s += base[(size_t)k*FS];
            smL[idx] = s * 0.015625f;
        }
    } else {
        for (int idx = t; idx < 2*FS; idx += 512) {
            const int col = (idx < FS) ? idx : idx - FS;
            const int r0  = (idx < FS) ? 0 : 16;
            const float* base = psumIn + (size_t)r0*NSV + col;
            float s = 0.f;
            #pragma unroll
            for (int k = 0; k < 16; ++k) s += base[(size_t)k*NSV];
            smL[idx] = s * 0.015625f;
        }
    }
    __syncthreads();

    {   // t1 partials over 8 waves: t1[o] = Vb[o] + smean . Vw[0:2FS]
        constexpr int TI = (2*FS)/8;
        float a1 = 0.f;
        const float* Wp = Vw + (size_t)(wv*TI)*NSV + o;
        const float* mp = smL + wv*TI;
        #pragma unroll 8
        for (int k = 0; k < TI; ++k) a1 = fmaf(mp[k], Wp[(size_t)k*NSV], a1);
        red[wv*64 + ol] = a1;
    }
    __syncthreads();
    if (t < 64) {
        float s = Vb[o0 + t];
        #pragma unroll
        for (int g = 0; g < 8; ++g) s += red[g*64 + t];
        t1L[t] = s;
    }
    __syncthreads();

    const int e_l = wv & 3, kh = wv >> 2;
    {   // main GEMM, K split in halves across wave groups
        float a2 = (kh == 0) ? t1L[ol] : 0.f;
        const float* Ap = As + e_l*KP + kh*KP2;          // wave-uniform base
        const float* Wp = Vw + (size_t)(2*FS + kh*KP2)*NSV + o;
        #pragma unroll 16
        for (int k = 0; k < KP2; ++k)
            a2 = fmaf(Ap[k], Wp[(size_t)k*NSV], a2);
        red[wv*64 + ol] = a2;
    }
    __syncthreads();
    float v = 0.f;
    if (t < 256) {
        v = tanhf(red[(t>>6)*64 + (t&63)] + red[((t>>6)+4)*64 + (t&63)]);
        svOut[(size_t)(e0 + (t>>6))*NSV + o0 + (t&63)] = v;
    }
    if (psumOut) {
        __syncthreads();
        if (t < 256) red[t] = v;
        __syncthreads();
        if (t < 64) {
            float s = red[t] + red[64+t] + red[128+t] + red[192+t];
            psumOut[(size_t)et*NSV + o0 + t] = s;        // unscaled col sums
        }
    }
}

// ---------------------------------------------------------------------------
// heads + orbital matrices, per electron. 128 blocks x 512 threads.
// ---------------------------------------------------------------------------
__global__ __launch_bounds__(512)
void headsw_kernel(const float* __restrict__ svF,
                   const float* __restrict__ vhu_w, const float* __restrict__ vhu_b,
                   const float* __restrict__ vhd_w, const float* __restrict__ vhd_b,
                   const float* __restrict__ wu_w,  const float* __restrict__ wu_b,
                   const float* __restrict__ wd_w,  const float* __restrict__ wd_b,
                   const float* __restrict__ expv,  float* __restrict__ orb)
{
    __shared__ __align__(16) float row[512];
    __shared__ __align__(16) float redH[512];
    __shared__ __align__(16) float tmpL[256];
    const int e = blockIdx.x;
    const int spin = e >> 6;
    const int t = threadIdx.x;
    row[t] = svF[(size_t)e*NSV + t];
    __syncthreads();

    const float* W1 = spin ? vhd_w : vhu_w;
    const float* B1 = spin ? vhd_b : vhu_b;
    {
        const int o = t & 255, kc = t >> 8;
        float acc = kc ? 0.f : B1[o];
        const float* Wp = W1 + (size_t)(kc*256)*256 + o;
        const float* rp = row + kc*256;
        #pragma unroll 8
        for (int f = 0; f < 256; ++f)
            acc = fmaf(rp[f], Wp[(size_t)f*256], acc);
        redH[t] = acc;
    }
    __syncthreads();
    if (t < 256) tmpL[t] = redH[t] + redH[256 + t];
    __syncthreads();

    const float* W2 = spin ? wd_w : wu_w;
    const float* B2 = spin ? wd_b : wu_b;
    {
        const int o = t & 63, kc = t >> 6;
        float acc = 0.f;
        const float* Wp = W2 + (size_t)(kc*32)*64 + o;
        const float* tp = tmpL + kc*32;
        #pragma unroll
        for (int f = 0; f < 32; ++f)
            acc = fmaf(tp[f], Wp[(size_t)f*64], acc);
        redH[kc*64 + o] = acc;
    }
    __syncthreads();
    if (t < 64) {
        float s = B2[t];
        #pragma unroll
        for (int g = 0; g < 8; ++g) s += redH[g*64 + t];
        orb[(size_t)e*64 + t] = s * expv[e];
    }
}

// ---------------------------------------------------------------------------
// det: two 64x64 log|det| via partial-pivot LU, one wave per matrix.
// DPP packed argmax, bit-cast v_readlane broadcasts, deferred log.
// ---------------------------------------------------------------------------
__device__ __forceinline__ int imax2(int a, int b) { return a > b ? a : b; }
__device__ __forceinline__ float readlane_f(float x, int lane) {
    return __int_as_float(__builtin_amdgcn_readlane(__float_as_int(x), lane));
}

__global__ __launch_bounds__(128)
void det_kernel(const float* __restrict__ orb, float* __restrict__ out)
{
    __shared__ float parts[2];
    const int t = threadIdx.x;
    const int w = t >> 6;
    const int lane = t & 63;
    const float* M = orb + (size_t)w*4096 + (size_t)lane*64;
    float rr[64];
    #pragma unroll
    for (int j = 0; j < 64; j += 4) {
        float4 v = *reinterpret_cast<const float4*>(M + j);
        rr[j]=v.x; rr[j+1]=v.y; rr[j+2]=v.z; rr[j+3]=v.w;
    }
    float pv_mine = 1.f;
    bool active = true;
    #pragma unroll
    for (int k = 0; k < 64; ++k) {
        int bits = (int)(__float_as_uint(rr[k]) & 0x7FFFFFC0u);
        int v = active ? (bits | lane) : lane;
        int tmp;
        tmp = __builtin_amdgcn_update_dpp(0, v, 0xB1,  0xF, 0xF, true); v = imax2(v, tmp);
        tmp = __builtin_amdgcn_update_dpp(0, v, 0x4E,  0xF, 0xF, true); v = imax2(v, tmp);
        tmp = __builtin_amdgcn_update_dpp(0, v, 0x141, 0xF, 0xF, true); v = imax2(v, tmp);
        tmp = __builtin_amdgcn_update_dpp(0, v, 0x140, 0xF, 0xF, true); v = imax2(v, tmp);
        tmp = __builtin_amdgcn_update_dpp(0, v, 0x142, 0xF, 0xF, true); v = imax2(v, tmp);
        tmp = __builtin_amdgcn_update_dpp(0, v, 0x143, 0xF, 0xF, true); v = imax2(v, tmp);
        const int idx = __builtin_amdgcn_readlane(v, 63) & 63;
        const float piv = readlane_f(rr[k], idx);
        pv_mine = (lane == k) ? piv : pv_mine;
        const float linv = __builtin_amdgcn_rcpf(piv);
        const float l = (active && lane != idx) ? rr[k]*linv : 0.f;
        if (lane == idx) active = false;
        #pragma unroll
        for (int j = k+1; j < 64; ++j)
            rr[j] = fmaf(-l, readlane_f(rr[j], idx), rr[j]);
    }
    float lg = logf(fabsf(pv_mine));
    #pragma unroll
    for (int off = 32; off; off >>= 1) lg += __shfl_down(lg, off);
    if (lane == 0) parts[w] = lg;
    __syncthreads();
    if (t == 0) out[0] = parts[0] + parts[1];
}

// ---------------------------------------------------------------------------
extern "C" void kernel_launch(void* const* d_in, const int* in_sizes, int n_in,
                              void* d_out, int out_size, void* d_ws, size_t ws_size,
                              hipStream_t stream)
{
    const float* r    = (const float*)d_in[0];
    const float* apos = (const float*)d_in[1];
    const float* V0w  = (const float*)d_in[2];
    const float* V0b  = (const float*)d_in[3];
    const float* W0w  = (const float*)d_in[4];
    const float* W0b  = (const float*)d_in[5];
    const float* V1w  = (const float*)d_in[6];
    const float* V1b  = (const float*)d_in[7];
    const float* W1w  = (const float*)d_in[8];
    const float* W1b  = (const float*)d_in[9];
    const float* V2w  = (const float*)d_in[10];
    const float* V2b  = (const float*)d_in[11];
    const float* W2w  = (const float*)d_in[12];
    const float* W2b  = (const float*)d_in[13];
    const float* afw  = (const float*)d_in[14];
    const float* afb  = (const float*)d_in[15];
    const float* vhuw = (const float*)d_in[16];
    const float* vhub = (const float*)d_in[17];
    const float* vhdw = (const float*)d_in[18];
    const float* vhdb = (const float*)d_in[19];
    const float* wuw  = (const float*)d_in[20];
    const float* wub  = (const float*)d_in[21];
    const float* wdw  = (const float*)d_in[22];
    const float* wdb  = (const float*)d_in[23];

    float* ws   = (float*)d_ws;
    float* sv0  = ws;              // 16384
    float* svA  = sv0  + 16384;    // 65536
    float* svB  = svA  + 65536;    // 65536
    float* expv = svB  + 65536;    // 128
    float* pme0 = expv + 128;      // 1024
    float* pme1 = pme0 + 1024;     // 16384
    float* pme2 = pme1 + 16384;    // 16384
    float* pme3 = pme2 + 16384;    // 16384
    float* psA  = pme3 + 16384;    // 16384
    float* psB  = psA  + 16384;    // 16384
    float* orb  = psB  + 16384;    // 8192

    pchain_kernel<<<128, 512, 0, stream>>>(r, apos, W0w, W0b, W1w, W1b, W2w, W2b,
                                           sv0, expv, pme0, pme1, pme2, pme3);
    a2_kernel<128, 4, true  ><<<256, 512, 0, stream>>>(sv0, pme0, nullptr, V0w, V0b, svA, psA);
    a2_kernel<512, 64, false><<<256, 512, 0, stream>>>(svA, pme1, psA, V1w, V1b, svB, psB);
    a2_kernel<512, 64, false><<<256, 512, 0, stream>>>(svB, pme2, psB, V2w, V2b, svA, psA);
    a2_kernel<512, 64, false><<<256, 512, 0, stream>>>(svA, pme3, psA, afw, afb, svB, nullptr);
    headsw_kernel<<<128, 512, 0, stream>>>(svB, vhuw, vhub, vhdw, vhdb,
                                           wuw, wub, wdw, wdb, expv, orb);
    det_kernel<<<1, 128, 0, stream>>>(orb, (float*)d_out);
}